// Round 18
// baseline (1138.210 us; speedup 1.0000x reference)
//
#include <hip/hip_runtime.h>
#include <cmath>

// ---------------- problem constants ----------------
constexpr int N = 20000, T = 13, E = 320000;
constexpr int NB_SCAN = (N + 255) / 256;   // 79
typedef unsigned int uint32;

typedef __attribute__((ext_vector_type(8))) short short8;   // 8 bf16 = 4 VGPRs
typedef __attribute__((ext_vector_type(4))) float f32x4;    // MFMA C/D frag

// ---------------- bf16 helpers ----------------
__device__ __forceinline__ unsigned short f2bf(float f) {
  unsigned int u = __float_as_uint(f);
  unsigned int r = (u + 0x7FFFu + ((u >> 16) & 1u)) >> 16;
  return (unsigned short)r;
}
__device__ __forceinline__ float bflo(uint32 v) { return __uint_as_float(v << 16); }
__device__ __forceinline__ float bfhi(uint32 v) { return __uint_as_float(v & 0xFFFF0000u); }
__device__ __forceinline__ uint32 packbf(float lo, float hi) {
  return (uint32)f2bf(lo) | ((uint32)f2bf(hi) << 16);
}

// ---------------- workspace layout ----------------
constexpr size_t WALIGN = 512;
constexpr size_t align_up(size_t x) { return (x + WALIGN - 1) & ~(WALIGN - 1); }

constexpr size_t XA_OFF  = 0;
constexpr size_t X_SZ    = align_up((size_t)N * 13 * 32 * 4);
constexpr size_t XB_OFF  = XA_OFF + X_SZ;
constexpr size_t H_OFF   = XB_OFF + X_SZ;
constexpr size_t H_SZ    = align_up((size_t)N * 12 * 32 * 4);
constexpr size_t C1_OFF  = H_OFF + H_SZ;
constexpr size_t C2_OFF  = C1_OFF + H_SZ;
constexpr size_t C3_OFF  = C2_OFF + H_SZ;
constexpr size_t HL_OFF  = C3_OFF + H_SZ;
constexpr size_t HL_SZ   = align_up((size_t)N * 256 * 4);
constexpr size_t WS2_OFF = HL_OFF + HL_SZ;
constexpr size_t SB_OFF  = WS2_OFF + align_up(256 * 256 * 4);
constexpr size_t SUMS_OFF = SB_OFF + align_up(256 * 4);
constexpr size_t PAR_OFF  = SUMS_OFF + align_up(8 * 64 * 4);
constexpr size_t CNT_OFF  = PAR_OFF + align_up(9 * 64 * 4);
constexpr size_t ROW_OFF  = CNT_OFF + align_up((size_t)N * 4);
constexpr size_t FILL_OFF = ROW_OFF + align_up((size_t)(N + 1) * 4);
constexpr size_t COL_OFF  = FILL_OFF + align_up((size_t)N * 4);
constexpr size_t DEG_OFF  = COL_OFF + align_up((size_t)E * 4);
constexpr size_t BP_OFF   = DEG_OFF + align_up((size_t)N * 4);   // gc_w B-frag pack
constexpr size_t CP_OFF   = BP_OFF + align_up(8 * 2048 * 4);     // conv W-frag pack
constexpr size_t BW1_OFF  = CP_OFF + align_up(8 * 2176 * 4);     // WS2 B-frag pack (O=256)
constexpr size_t BW2_OFF  = BW1_OFF + align_up(32768 * 4);       // out1_w B-frag pack (O=512)
constexpr size_t BS_OFF   = BW2_OFF + align_up(65536 * 4);       // scan partials
constexpr size_t BO_OFF   = BS_OFF + align_up((size_t)NB_SCAN * 4); // scan offsets
// aliases used after all layers are done:
constexpr size_t S_OFF  = C2_OFF;   // N*256 floats
constexpr size_t Y1_OFF = H_OFF;    // N*512 floats (spans H+C1)

// ---------------- CSR build ----------------
__global__ void k_count(const int* __restrict__ dst, int* __restrict__ cnt) {
  int i = blockIdx.x * 256 + threadIdx.x;
  if (i < E) atomicAdd(&cnt[dst[i]], 1);
}

// parallel scan, phase 1: per-block sums
__global__ __launch_bounds__(256) void k_scan1(const int* __restrict__ cnt, int* __restrict__ bsum) {
  __shared__ int sc[256];
  int t = threadIdx.x; int idx = blockIdx.x * 256 + t;
  int v = (idx < N) ? cnt[idx] : 0;
  sc[t] = v; __syncthreads();
  for (int off = 1; off < 256; off <<= 1) {
    int u = (t >= off) ? sc[t - off] : 0;
    __syncthreads();
    sc[t] += u;
    __syncthreads();
  }
  if (t == 255) bsum[blockIdx.x] = sc[255];
}

// phase 2: exclusive scan of block sums (1 tiny block)
__global__ __launch_bounds__(256) void k_scan2(const int* __restrict__ bsum, int* __restrict__ boff) {
  __shared__ int sc[256];
  int t = threadIdx.x;
  int v = (t < NB_SCAN) ? bsum[t] : 0;
  sc[t] = v; __syncthreads();
  for (int off = 1; off < 256; off <<= 1) {
    int u = (t >= off) ? sc[t - off] : 0;
    __syncthreads();
    sc[t] += u;
    __syncthreads();
  }
  if (t < NB_SCAN) boff[t] = sc[t] - v;
  if (t == 255) boff[NB_SCAN] = sc[255];   // total
}

// phase 3: per-block exclusive scan + apply offsets
__global__ __launch_bounds__(256) void k_scan3(const int* __restrict__ cnt, const int* __restrict__ boff,
                                               int* __restrict__ rowptr, int* __restrict__ fill,
                                               float* __restrict__ deginv) {
  __shared__ int sc[256];
  int t = threadIdx.x; int idx = blockIdx.x * 256 + t;
  int v = (idx < N) ? cnt[idx] : 0;
  sc[t] = v; __syncthreads();
  for (int off = 1; off < 256; off <<= 1) {
    int u = (t >= off) ? sc[t - off] : 0;
    __syncthreads();
    sc[t] += u;
    __syncthreads();
  }
  if (idx < N) {
    int run = boff[blockIdx.x] + sc[t] - v;
    rowptr[idx] = run; fill[idx] = run;
    deginv[idx] = 1.0f / (float)(v > 1 ? v : 1);
  }
  if (blockIdx.x == 0 && t == 0) rowptr[N] = boff[NB_SCAN];
}

__global__ void k_scatter(const int* __restrict__ src, const int* __restrict__ dst,
                          int* __restrict__ fill, int* __restrict__ col) {
  int i = blockIdx.x * 256 + threadIdx.x;
  if (i < E) { int d = dst[i]; int p = atomicAdd(&fill[d], 1); col[p] = src[i]; }
}

__global__ void k_init_params(float* __restrict__ par) {
  int i = threadIdx.x;                 // 64 threads: slot 0 = identity affine
  par[i] = (i < 32) ? 1.0f : 0.0f;
}

// ---------------- pack gc_w into bf16 MFMA B-fragments (verified layout) ----------------
__global__ void k_prep_gcw(const float* __restrict__ gcw, uint32* __restrict__ bp) {
  int idx = blockIdx.x * 256 + threadIdx.x;
  if (idx >= 8 * 4 * 2 * 64 * 4) return;
  int w4 = idx & 3, lane = (idx >> 2) & 63, hh = (idx >> 8) & 1, s = (idx >> 9) & 3, l = idx >> 11;
  int n = lane & 15, q = lane >> 4;
  int k0 = q * 8 + w4 * 2, o = hh * 16 + n;
  const float* g = gcw + (((size_t)(l * 4 + s) * 32 + k0) * 32 + o);
  bp[idx] = packbf(g[0], g[32]);
}

// ---------------- pack a [O][256] fp32 weight into bf16 B-fragments ----------------
__global__ void k_prep_bw(const float* __restrict__ W, uint32* __restrict__ bp, int O) {
  int idx = blockIdx.x * 256 + threadIdx.x;
  int total = (O / 16) * 8 * 64 * 4;
  if (idx >= total) return;
  int w4 = idx & 3, lane = (idx >> 2) & 63, ks = (idx >> 8) & 7, ot = idx >> 11;
  int n = lane & 15, q = lane >> 4;
  int k = ks * 32 + q * 8 + w4 * 2;
  const float* wr = W + (size_t)(ot * 16 + n) * 256 + k;
  bp[idx] = packbf(wr[0], wr[1]);
}

// ---------------- pack conv weights (affine-folded) into bf16 B-fragments + biases ----------------
__global__ void k_prep_conv(const float* __restrict__ fw, const float* __restrict__ fb,
                            const float* __restrict__ gw, const float* __restrict__ gb,
                            const float* __restrict__ par, int layer, uint32* __restrict__ cpbuf) {
  uint32* base = cpbuf + (size_t)layer * 2176;
  int tid = blockIdx.x * 256 + threadIdx.x;
  if (tid < 2048) {
    int w4 = tid & 3, lane = (tid >> 2) & 63, hh = (tid >> 8) & 1, ktap = (tid >> 9) & 1, sel = tid >> 10;
    int n = lane & 15, q = lane >> 4;
    int c0 = q * 8 + w4 * 2, o = hh * 16 + n;
    const float* w = sel ? gw : fw;
    float sc0 = par[layer * 64 + c0], sc1 = par[layer * 64 + c0 + 1];
    float v0 = w[(((size_t)layer * 32 + o) * 32 + c0) * 2 + ktap] * sc0;
    float v1 = w[(((size_t)layer * 32 + o) * 32 + c0 + 1) * 2 + ktap] * sc1;
    base[tid] = packbf(v0, v1);
  } else if (tid < 2048 + 64) {
    int i = tid - 2048; int sel = i >> 5; int o = i & 31;
    const float* w = sel ? gw : fw;
    const float* b = sel ? gb : fb;
    float s = b[layer * 32 + o];
    for (int c = 0; c < 32; c++) {
      float sh = par[layer * 64 + 32 + c];
      s += (w[(((size_t)layer * 32 + o) * 32 + c) * 2 + 0] +
            w[(((size_t)layer * 32 + o) * 32 + c) * 2 + 1]) * sh;
    }
    ((float*)base)[2048 + i] = s;
  }
}

// ---------------- enter 1x1 conv: inputs [N,T,3] -> x bf16 [n][t][c] ----------------
__global__ void k_enter(const float* __restrict__ in, const float* __restrict__ w,
                        const float* __restrict__ b, uint32* __restrict__ x) {
  int idx = blockIdx.x * 256 + threadIdx.x;
  if (idx >= N * 13 * 16) return;
  int cw = idx & 15; int tmp = idx >> 4; int t = tmp % 13; int n = tmp / 13;
  int c0 = cw * 2;
  const float* ip = in + (size_t)n * (13 * 3) + t * 3;
  float v0 = b[c0]     + w[c0 * 3 + 0]       * ip[0] + w[c0 * 3 + 1]       * ip[1] + w[c0 * 3 + 2]       * ip[2];
  float v1 = b[c0 + 1] + w[(c0 + 1) * 3 + 0] * ip[0] + w[(c0 + 1) * 3 + 1] * ip[1] + w[(c0 + 1) * 3 + 2] * ip[2];
  x[idx] = packbf(v0, v1);
}

// ---------------- gated dilated conv (MFMA) — round-15 proven form ----------------
template <int TIN, int TOUT, int D>
__global__ __launch_bounds__(256, 4) void k_conv(const uint32* __restrict__ x,
    const uint32* __restrict__ cpbuf, int layer,
    uint32* __restrict__ h, float* __restrict__ hlast) {
  constexpr int RS = 34;
  __shared__ float xst[128 * RS];
  int tid = threadIdx.x;
  int wave = tid >> 6, lane = tid & 63;
  int m = lane & 15, q = lane >> 4;
  int nrows = N * TOUT;
  int base = blockIdx.x * 128;

  const uint32* cp = cpbuf + (size_t)layer * 2176;
  short8 bf[2][2][2];   // [sel][ktap][hh]
#pragma unroll
  for (int sel = 0; sel < 2; sel++)
#pragma unroll
    for (int kt = 0; kt < 2; kt++)
#pragma unroll
      for (int hh = 0; hh < 2; hh++)
        bf[sel][kt][hh] = *(const short8*)(cp + (size_t)(((sel * 2 + kt) * 2 + hh) * 64 + lane) * 4);
  const float* bias = (const float*)(cp + 2048);
  float fb0 = bias[m], fb1 = bias[16 + m], gb0 = bias[32 + m], gb1 = bias[48 + m];

#pragma unroll
  for (int tile = 0; tile < 2; tile++) {
    int row = base + wave * 32 + tile * 16 + m;
    bool valid = row < nrows;
    int rr = valid ? row : 0;
    int n = rr / TOUT, tt = rr - n * TOUT;
    const uint32* xr = x + ((size_t)n * TIN + tt) * 16 + q * 4;
    short8 a0 = {0,0,0,0,0,0,0,0}, aD = {0,0,0,0,0,0,0,0};
    if (valid) { a0 = *(const short8*)xr; aD = *(const short8*)(xr + D * 16); }
    f32x4 aF0 = {0.f,0.f,0.f,0.f}, aF1 = {0.f,0.f,0.f,0.f};
    f32x4 aG0 = {0.f,0.f,0.f,0.f}, aG1 = {0.f,0.f,0.f,0.f};
    aF0 = __builtin_amdgcn_mfma_f32_16x16x32_bf16(a0, bf[0][0][0], aF0, 0, 0, 0);
    aF0 = __builtin_amdgcn_mfma_f32_16x16x32_bf16(aD, bf[0][1][0], aF0, 0, 0, 0);
    aF1 = __builtin_amdgcn_mfma_f32_16x16x32_bf16(a0, bf[0][0][1], aF1, 0, 0, 0);
    aF1 = __builtin_amdgcn_mfma_f32_16x16x32_bf16(aD, bf[0][1][1], aF1, 0, 0, 0);
    aG0 = __builtin_amdgcn_mfma_f32_16x16x32_bf16(a0, bf[1][0][0], aG0, 0, 0, 0);
    aG0 = __builtin_amdgcn_mfma_f32_16x16x32_bf16(aD, bf[1][1][0], aG0, 0, 0, 0);
    aG1 = __builtin_amdgcn_mfma_f32_16x16x32_bf16(a0, bf[1][0][1], aG1, 0, 0, 0);
    aG1 = __builtin_amdgcn_mfma_f32_16x16x32_bf16(aD, bf[1][1][1], aG1, 0, 0, 0);
#pragma unroll
    for (int r = 0; r < 4; r++) {
      int lrow = wave * 32 + tile * 16 + q * 4 + r;
      float F0 = aF0[r] + fb0, G0 = aG0[r] + gb0;
      float F1 = aF1[r] + fb1, G1 = aG1[r] + gb1;
      float af0 = fabsf(F0), ef0 = __expf(-2.0f * af0);
      float th0 = copysignf((1.0f - ef0) / (1.0f + ef0), F0);
      float hv0 = th0 * (1.0f / (1.0f + __expf(-G0)));
      float af1 = fabsf(F1), ef1 = __expf(-2.0f * af1);
      float th1 = copysignf((1.0f - ef1) / (1.0f + ef1), F1);
      float hv1 = th1 * (1.0f / (1.0f + __expf(-G1)));
      xst[lrow * RS + m]      = hv0;
      xst[lrow * RS + 16 + m] = hv1;
    }
  }
  __syncthreads();
  {
    uint2* outp = (uint2*)h;
#pragma unroll
    for (int it = 0; it < 4; it++) {
      int l = it * 256 + tid;
      int g = base * 8 + l;
      if (g < nrows * 8) {
        int rl = l >> 3, j4 = l & 7;
        float2 a = *(const float2*)&xst[rl * RS + j4 * 4];
        float2 b = *(const float2*)&xst[rl * RS + j4 * 4 + 2];
        outp[g] = make_uint2(packbf(a.x, a.y), packbf(b.x, b.y));
        int grow = base + rl;
        int node = grow / TOUT, tt = grow - node * TOUT;
        if (tt == TOUT - 1) {
          *(float4*)(hlast + (size_t)node * 256 + layer * 32 + j4 * 4) = make_float4(a.x, a.y, b.x, b.y);
        }
      }
    }
  }
}

// ---------------- one diffusion hop (bf16, fp32 accumulate, x8 edge unroll) ----------------
template <int F>
__global__ __launch_bounds__(256) void k_hop(const uint32* __restrict__ in, uint32* __restrict__ out,
    const int* __restrict__ rowptr, const int* __restrict__ col, const float* __restrict__ deginv) {
  constexpr int F2 = F / 2;
  constexpr int NW = (F2 + 63) / 64;
  int wid = (blockIdx.x * 256 + threadIdx.x) >> 6;
  int lane = threadIdx.x & 63;
  if (wid >= N) return;
  int s = rowptr[wid], e = rowptr[wid + 1];
  float alo[NW], ahi[NW];
#pragma unroll
  for (int k = 0; k < NW; k++) { alo[k] = 0.0f; ahi[k] = 0.0f; }
  int idx = s;
  for (; idx + 7 < e; idx += 8) {
    const uint32* p[8];
#pragma unroll
    for (int q = 0; q < 8; q++) p[q] = in + (size_t)col[idx + q] * F2;
    uint32 v[8][NW];
#pragma unroll
    for (int q = 0; q < 8; q++) {
#pragma unroll
      for (int k = 0; k < NW; k++) {
        int j = k * 64 + lane;
        v[q][k] = (j < F2) ? p[q][j] : 0u;
      }
    }
#pragma unroll
    for (int k = 0; k < NW; k++) {
      alo[k] += ((bflo(v[0][k]) + bflo(v[1][k])) + (bflo(v[2][k]) + bflo(v[3][k]))) +
                ((bflo(v[4][k]) + bflo(v[5][k])) + (bflo(v[6][k]) + bflo(v[7][k])));
      ahi[k] += ((bfhi(v[0][k]) + bfhi(v[1][k])) + (bfhi(v[2][k]) + bfhi(v[3][k]))) +
                ((bfhi(v[4][k]) + bfhi(v[5][k])) + (bfhi(v[6][k]) + bfhi(v[7][k])));
    }
  }
  for (; idx + 3 < e; idx += 4) {
    const uint32* p0 = in + (size_t)col[idx] * F2;
    const uint32* p1 = in + (size_t)col[idx + 1] * F2;
    const uint32* p2 = in + (size_t)col[idx + 2] * F2;
    const uint32* p3 = in + (size_t)col[idx + 3] * F2;
#pragma unroll
    for (int k = 0; k < NW; k++) {
      int j = k * 64 + lane;
      if (j < F2) {
        uint32 v0 = p0[j], v1 = p1[j], v2 = p2[j], v3 = p3[j];
        alo[k] += (bflo(v0) + bflo(v1)) + (bflo(v2) + bflo(v3));
        ahi[k] += (bfhi(v0) + bfhi(v1)) + (bfhi(v2) + bfhi(v3));
      }
    }
  }
  for (; idx < e; ++idx) {
    const uint32* p = in + (size_t)col[idx] * F2;
#pragma unroll
    for (int k = 0; k < NW; k++) {
      int j = k * 64 + lane;
      if (j < F2) { uint32 v = p[j]; alo[k] += bflo(v); ahi[k] += bfhi(v); }
    }
  }
  float inv = deginv[wid];
  uint32* q = out + (size_t)wid * F2;
#pragma unroll
  for (int k = 0; k < NW; k++) {
    int j = k * 64 + lane;
    if (j < F2) q[j] = packbf(alo[k] * inv, ahi[k] * inv);
  }
}

// ---------------- combine (MFMA) — round-15 form + VGPR headroom (4 blocks/CU, cap 128) ----------------
template <int TIN, int TOUT>
__global__ __launch_bounds__(256, 4) void k_combine(const uint32* __restrict__ h,
    const uint32* __restrict__ c1, const uint32* __restrict__ c2, const uint32* __restrict__ c3,
    const uint32* __restrict__ bpack, const float* __restrict__ gcb,
    const uint32* __restrict__ xcur, int layer,
    const float* __restrict__ par, int slot,
    uint32* __restrict__ xnext, float* __restrict__ sums) {
  constexpr int RS = 34;
  __shared__ float xst[128 * RS];
  __shared__ float pbuf[96];
  __shared__ float r1s[32], r2s[32];
  int tid = threadIdx.x;
  if (tid < 32) {
    pbuf[tid]      = gcb[layer * 32 + tid];
    pbuf[32 + tid] = par[slot * 64 + tid];
    pbuf[64 + tid] = par[slot * 64 + 32 + tid];
    r1s[tid] = 0.0f; r2s[tid] = 0.0f;
  }

  int nrows = N * TOUT;
  int base = blockIdx.x * 128;
  int wave = tid >> 6, lane = tid & 63;
  int m = lane & 15, q = lane >> 4;

  const uint32* bp = bpack + (size_t)layer * 2048;
  short8 bf[4][2];
#pragma unroll
  for (int s = 0; s < 4; s++)
#pragma unroll
    for (int hh = 0; hh < 2; hh++)
      bf[s][hh] = *(const short8*)(bp + (size_t)((s * 2 + hh) * 64 + lane) * 4);

  f32x4 acc[2][2] = {{{0.f,0.f,0.f,0.f},{0.f,0.f,0.f,0.f}},{{0.f,0.f,0.f,0.f},{0.f,0.f,0.f,0.f}}};
  const uint32* srcs[4] = { h, c1, c2, c3 };
#pragma unroll
  for (int s = 0; s < 4; s++) {
    const uint32* sp = srcs[s];
#pragma unroll
    for (int t = 0; t < 2; t++) {
      int row = base + wave * 32 + t * 16 + m;
      short8 af = {0,0,0,0,0,0,0,0};
      if (row < nrows) af = *(const short8*)(sp + (size_t)row * 16 + q * 4);
      acc[t][0] = __builtin_amdgcn_mfma_f32_16x16x32_bf16(af, bf[s][0], acc[t][0], 0, 0, 0);
      acc[t][1] = __builtin_amdgcn_mfma_f32_16x16x32_bf16(af, bf[s][1], acc[t][1], 0, 0, 0);
    }
  }

  __syncthreads();
#pragma unroll
  for (int t = 0; t < 2; t++)
#pragma unroll
    for (int hh = 0; hh < 2; hh++)
#pragma unroll
      for (int r = 0; r < 4; r++)
        xst[(wave * 32 + t * 16 + q * 4 + r) * RS + hh * 16 + m] = acc[t][hh][r];
  __syncthreads();

  constexpr int toff = TIN - TOUT;
  int rg = tid >> 3, oq = tid & 7;
  float gb0 = pbuf[oq * 4 + 0], gb1 = pbuf[oq * 4 + 1], gb2 = pbuf[oq * 4 + 2], gb3 = pbuf[oq * 4 + 3];
  float sc0 = pbuf[32 + oq * 4 + 0], sc1 = pbuf[32 + oq * 4 + 1], sc2 = pbuf[32 + oq * 4 + 2], sc3 = pbuf[32 + oq * 4 + 3];
  float sh0 = pbuf[64 + oq * 4 + 0], sh1 = pbuf[64 + oq * 4 + 1], sh2 = pbuf[64 + oq * 4 + 2], sh3 = pbuf[64 + oq * 4 + 3];
  float s1[4] = {0.f, 0.f, 0.f, 0.f}, s2[4] = {0.f, 0.f, 0.f, 0.f};
#pragma unroll
  for (int i = 0; i < 4; i++) {
    int r = rg + 32 * i;
    int row = base + r;
    bool act = row < nrows;
    float2 aa = *(const float2*)&xst[r * RS + oq * 4];
    float2 ab = *(const float2*)&xst[r * RS + oq * 4 + 2];
    float xr0 = 0.f, xr1 = 0.f, xr2 = 0.f, xr3 = 0.f;
    if (act) {
      int node = row / TOUT, t_ = row - node * TOUT;
      const uint32* rp = xcur + ((size_t)node * TIN + toff + t_) * 16 + oq * 2;
      uint32 va = rp[0], vb = rp[1];
      xr0 = bflo(va); xr1 = bfhi(va); xr2 = bflo(vb); xr3 = bfhi(vb);
    }
    float v0 = aa.x + gb0 + sc0 * xr0 + sh0;
    float v1 = aa.y + gb1 + sc1 * xr1 + sh1;
    float v2 = ab.x + gb2 + sc2 * xr2 + sh2;
    float v3 = ab.y + gb3 + sc3 * xr3 + sh3;
    *(float2*)&xst[r * RS + oq * 4]     = make_float2(v0, v1);
    *(float2*)&xst[r * RS + oq * 4 + 2] = make_float2(v2, v3);
    if (act) {
      s1[0] += v0; s1[1] += v1; s1[2] += v2; s1[3] += v3;
      s2[0] += v0 * v0; s2[1] += v1 * v1; s2[2] += v2 * v2; s2[3] += v3 * v3;
    }
  }
#pragma unroll
  for (int j = 0; j < 4; j++) {
    atomicAdd(&r1s[oq * 4 + j], s1[j]);
    atomicAdd(&r2s[oq * 4 + j], s2[j]);
  }
  __syncthreads();

  {
    uint2* outp = (uint2*)xnext;
#pragma unroll
    for (int it = 0; it < 4; it++) {
      int l = it * 256 + tid;
      int g = base * 8 + l;
      if (g < nrows * 8) {
        int rl = l >> 3, j4 = l & 7;
        float2 a = *(const float2*)&xst[rl * RS + j4 * 4];
        float2 b = *(const float2*)&xst[rl * RS + j4 * 4 + 2];
        outp[g] = make_uint2(packbf(a.x, a.y), packbf(b.x, b.y));
      }
    }
  }
  if (tid < 32) atomicAdd(&sums[layer * 64 + tid], r1s[tid]);
  else if (tid < 64) atomicAdd(&sums[layer * 64 + tid], r2s[tid - 32]);
}

// ---------------- BN stats -> affine params for next slot ----------------
__global__ void k_bnfin(const float* __restrict__ sums, const float* __restrict__ bng,
                        const float* __restrict__ bnb, float* __restrict__ par,
                        int layer, int tout) {
  int o = threadIdx.x;  // 32
  float cnt = (float)N * (float)tout;
  float s1 = sums[layer * 64 + o], s2 = sums[layer * 64 + 32 + o];
  float mu = s1 / cnt;
  float var = s2 / cnt - mu * mu;
  float sc = bng[layer * 32 + o] * rsqrtf(var + 1e-5f);
  par[(layer + 1) * 64 + o] = sc;
  par[(layer + 1) * 64 + 32 + o] = bnb[layer * 32 + o] - mu * sc;
}

// ---------------- head prep ----------------
__global__ void k_prep_skipw(const float* __restrict__ sw, float* __restrict__ w2) {
  int idx = blockIdx.x * 256 + threadIdx.x;
  if (idx >= 8 * 256 * 32) return;
  int l = idx / (256 * 32), r = idx % (256 * 32), o = r / 32, c = r & 31;
  w2[o * 256 + l * 32 + c] = sw[idx];
}
__global__ void k_prep_sb(const float* __restrict__ sb, float* __restrict__ out) {
  int o = threadIdx.x;  // 256
  float s = 0.0f;
  for (int l = 0; l < 8; l++) s += sb[l * 256 + o];
  out[o] = s;
}

// ---------------- head GEMM (MFMA) ----------------
__global__ __launch_bounds__(256) void k_mgemm(const float* __restrict__ A, const uint32* __restrict__ bp,
    const float* __restrict__ bias, float* __restrict__ C, int M, int Onum, int relu) {
  constexpr int RS = 68;
  __shared__ float xst[128 * RS];
  int tid = threadIdx.x;
  int wave = tid >> 6, lane = tid & 63;
  int m = lane & 15, q = lane >> 4;
  int base = blockIdx.x * 128;
  int ot0 = blockIdx.y * 4;

  f32x4 acc[2][4];
#pragma unroll
  for (int t = 0; t < 2; t++)
#pragma unroll
    for (int nt = 0; nt < 4; nt++) acc[t][nt] = (f32x4){0.f, 0.f, 0.f, 0.f};

#pragma unroll 1
  for (int ks = 0; ks < 8; ks++) {
    short8 a[2];
#pragma unroll
    for (int t = 0; t < 2; t++) {
      int row = base + wave * 32 + t * 16 + m;
      float4 f0 = make_float4(0.f, 0.f, 0.f, 0.f), f1 = f0;
      if (row < M) {
        const float* ap = A + (size_t)row * 256 + ks * 32 + q * 8;
        f0 = *(const float4*)ap;
        f1 = *(const float4*)(ap + 4);
      }
      uint32 u[4];
      u[0] = packbf(f0.x, f0.y); u[1] = packbf(f0.z, f0.w);
      u[2] = packbf(f1.x, f1.y); u[3] = packbf(f1.z, f1.w);
      a[t] = *(const short8*)u;
    }
#pragma unroll
    for (int nt = 0; nt < 4; nt++) {
      short8 b = *(const short8*)(bp + (size_t)(((ot0 + nt) * 8 + ks) * 64 + lane) * 4);
      acc[0][nt] = __builtin_amdgcn_mfma_f32_16x16x32_bf16(a[0], b, acc[0][nt], 0, 0, 0);
      acc[1][nt] = __builtin_amdgcn_mfma_f32_16x16x32_bf16(a[1], b, acc[1][nt], 0, 0, 0);
    }
  }

#pragma unroll
  for (int t = 0; t < 2; t++)
#pragma unroll
    for (int nt = 0; nt < 4; nt++) {
      float bv = bias[blockIdx.y * 64 + nt * 16 + m];
#pragma unroll
      for (int r = 0; r < 4; r++) {
        float v = acc[t][nt][r] + bv;
        if (relu) v = fmaxf(v, 0.0f);
        xst[(wave * 32 + t * 16 + q * 4 + r) * RS + nt * 16 + m] = v;
      }
    }
  __syncthreads();

#pragma unroll
  for (int it = 0; it < 8; it++) {
    int l = it * 256 + tid;
    int rl = l >> 4, c4 = l & 15;
    int grow = base + rl;
    if (grow < M) {
      float4 v = *(const float4*)&xst[rl * RS + c4 * 4];
      *(float4*)(C + (size_t)grow * Onum + blockIdx.y * 64 + c4 * 4) = v;
    }
  }
}

// ---------------- final: K-split tiled GEMM with atomic reduce -> d_out [N,24] ----------------
__global__ __launch_bounds__(256) void k_final2(const float* __restrict__ Y1, const float* __restrict__ W2,
                                                const float* __restrict__ b2, float* __restrict__ out) {
  __shared__ float y1s[64][68];
  __shared__ float w2s[24][65];
  int tid = threadIdx.x;
  int bm = blockIdx.x * 64;
  int k0 = blockIdx.y * 64;
  for (int i = tid; i < 64 * 16; i += 256) {
    int r = i >> 4, k4 = i & 15;
    int gm = bm + r;
    float4 v = make_float4(0.f, 0.f, 0.f, 0.f);
    if (gm < N) v = *(const float4*)(Y1 + (size_t)gm * 512 + k0 + k4 * 4);
    y1s[r][k4 * 4 + 0] = v.x; y1s[r][k4 * 4 + 1] = v.y;
    y1s[r][k4 * 4 + 2] = v.z; y1s[r][k4 * 4 + 3] = v.w;
  }
  for (int i = tid; i < 24 * 16; i += 256) {
    int o = i >> 4, k4 = i & 15;
    float4 v = *(const float4*)(W2 + (size_t)o * 512 + k0 + k4 * 4);
    w2s[o][k4 * 4 + 0] = v.x; w2s[o][k4 * 4 + 1] = v.y;
    w2s[o][k4 * 4 + 2] = v.z; w2s[o][k4 * 4 + 3] = v.w;
  }
  __syncthreads();
  int rg = tid >> 5;
  int o = tid & 31;
  if (o < 24) {
    float acc[8] = {};
    for (int kk = 0; kk < 64; kk++) {
      float w = w2s[o][kk];
#pragma unroll
      for (int i = 0; i < 8; i++) acc[i] += y1s[rg * 8 + i][kk] * w;
    }
    float bias = (blockIdx.y == 0) ? b2[o] : 0.0f;
#pragma unroll
    for (int i = 0; i < 8; i++) {
      int gm = bm + rg * 8 + i;
      if (gm < N) atomicAdd(&out[(size_t)gm * 24 + o], acc[i] + bias);
    }
  }
}

// ---------------- host side ----------------
struct Ptrs {
  const float *fw, *fb, *gw, *gb, *gcb, *bng, *bnb;
  const uint32 *bpack;
  uint32 *cpack;
  void *H, *C1, *C2, *C3;
  float *HL, *par, *sums;
  const int *row, *col;
  const float *deg;
};

template <int TIN, int TOUT, int D>
static void run_layer(int layer, bool last, const Ptrs& P, uint32*& xc, uint32*& xn, hipStream_t stream) {
  int cblocks = (N * TOUT + 127) / 128;
  k_conv<TIN, TOUT, D><<<cblocks, 256, 0, stream>>>(xc, P.cpack, layer, (uint32*)P.H, P.HL);
  if (!last) {
    constexpr int F = TOUT * 32;
    int hb = (N * 64 + 255) / 256;
    k_hop<F><<<hb, 256, 0, stream>>>((const uint32*)P.H, (uint32*)P.C1, P.row, P.col, P.deg);
    k_hop<F><<<hb, 256, 0, stream>>>((const uint32*)P.C1, (uint32*)P.C2, P.row, P.col, P.deg);
    k_hop<F><<<hb, 256, 0, stream>>>((const uint32*)P.C2, (uint32*)P.C3, P.row, P.col, P.deg);
    k_combine<TIN, TOUT><<<cblocks, 256, 0, stream>>>((const uint32*)P.H, (const uint32*)P.C1,
                                                      (const uint32*)P.C2, (const uint32*)P.C3,
                                                      P.bpack, P.gcb, xc, layer, P.par, layer, xn, P.sums);
    k_bnfin<<<1, 32, 0, stream>>>(P.sums, P.bng, P.bnb, P.par, layer, TOUT);
    k_prep_conv<<<9, 256, 0, stream>>>(P.fw, P.fb, P.gw, P.gb, P.par, layer + 1, P.cpack);
    uint32* tmp = xc; xc = xn; xn = tmp;
  }
}

extern "C" void kernel_launch(void* const* d_in, const int* in_sizes, int n_in,
                              void* d_out, int out_size, void* d_ws, size_t ws_size,
                              hipStream_t stream) {
  const float* inputs  = (const float*)d_in[0];
  const int*   esrc    = (const int*)d_in[1];
  const int*   edst    = (const int*)d_in[2];
  const float* enter_w = (const float*)d_in[3];
  const float* enter_b = (const float*)d_in[4];
  const float* filt_w  = (const float*)d_in[5];
  const float* filt_b  = (const float*)d_in[6];
  const float* gate_w  = (const float*)d_in[7];
  const float* gate_b  = (const float*)d_in[8];
  const float* gc_w    = (const float*)d_in[9];
  const float* gc_b    = (const float*)d_in[10];
  const float* skip_w  = (const float*)d_in[11];
  const float* skip_b  = (const float*)d_in[12];
  const float* bn_g    = (const float*)d_in[13];
  const float* bn_b    = (const float*)d_in[14];
  const float* out1_w  = (const float*)d_in[15];
  const float* out1_b  = (const float*)d_in[16];
  const float* out2_w  = (const float*)d_in[17];
  const float* out2_b  = (const float*)d_in[18];

  char* ws = (char*)d_ws;
  uint32* XA = (uint32*)(ws + XA_OFF);
  uint32* XB = (uint32*)(ws + XB_OFF);
  void* H    = (void*)(ws + H_OFF);
  void* C1   = (void*)(ws + C1_OFF);
  void* C2   = (void*)(ws + C2_OFF);
  void* C3   = (void*)(ws + C3_OFF);
  float* HL  = (float*)(ws + HL_OFF);
  float* WS2 = (float*)(ws + WS2_OFF);
  float* SB  = (float*)(ws + SB_OFF);
  float* SUMS = (float*)(ws + SUMS_OFF);
  float* PAR  = (float*)(ws + PAR_OFF);
  int* CNT  = (int*)(ws + CNT_OFF);
  int* ROW  = (int*)(ws + ROW_OFF);
  int* FILL = (int*)(ws + FILL_OFF);
  int* COL  = (int*)(ws + COL_OFF);
  float* DEG = (float*)(ws + DEG_OFF);
  uint32* BP = (uint32*)(ws + BP_OFF);
  uint32* CP = (uint32*)(ws + CP_OFF);
  uint32* BW1 = (uint32*)(ws + BW1_OFF);
  uint32* BW2 = (uint32*)(ws + BW2_OFF);
  int* BS = (int*)(ws + BS_OFF);
  int* BO = (int*)(ws + BO_OFF);
  float* S  = (float*)(ws + S_OFF);
  float* Y1 = (float*)(ws + Y1_OFF);

  hipMemsetAsync(CNT, 0, (size_t)N * 4, stream);
  hipMemsetAsync(SUMS, 0, 8 * 64 * 4, stream);
  hipMemsetAsync(d_out, 0, (size_t)out_size * 4, stream);

  k_count<<<(E + 255) / 256, 256, 0, stream>>>(edst, CNT);
  k_scan1<<<NB_SCAN, 256, 0, stream>>>(CNT, BS);
  k_scan2<<<1, 256, 0, stream>>>(BS, BO);
  k_scan3<<<NB_SCAN, 256, 0, stream>>>(CNT, BO, ROW, FILL, DEG);
  k_scatter<<<(E + 255) / 256, 256, 0, stream>>>(esrc, edst, FILL, COL);
  k_init_params<<<1, 64, 0, stream>>>(PAR);
  k_prep_gcw<<<(8 * 4 * 2 * 64 * 4 + 255) / 256, 256, 0, stream>>>(gc_w, BP);
  k_prep_conv<<<9, 256, 0, stream>>>(filt_w, filt_b, gate_w, gate_b, PAR, 0, CP);
  k_enter<<<(N * 13 * 16 + 255) / 256, 256, 0, stream>>>(inputs, enter_w, enter_b, XA);
  k_prep_skipw<<<(8 * 256 * 32 + 255) / 256, 256, 0, stream>>>(skip_w, WS2);
  k_prep_sb<<<1, 256, 0, stream>>>(skip_b, SB);
  k_prep_bw<<<(32768 + 255) / 256, 256, 0, stream>>>(WS2, BW1, 256);
  k_prep_bw<<<(65536 + 255) / 256, 256, 0, stream>>>(out1_w, BW2, 512);

  Ptrs P;
  P.fw = filt_w; P.fb = filt_b; P.gw = gate_w; P.gb = gate_b;
  P.gcb = gc_b; P.bng = bn_g; P.bnb = bn_b; P.bpack = BP; P.cpack = CP;
  P.H = H; P.C1 = C1; P.C2 = C2; P.C3 = C3; P.HL = HL; P.par = PAR; P.sums = SUMS;
  P.row = ROW; P.col = COL; P.deg = DEG;

  uint32* xc = XA; uint32* xn = XB;
  run_layer<13, 12, 1>(0, false, P, xc, xn, stream);
  run_layer<12, 10, 2>(1, false, P, xc, xn, stream);
  run_layer<10, 9, 1>(2, false, P, xc, xn, stream);
  run_layer<9, 7, 2>(3, false, P, xc, xn, stream);
  run_layer<7, 6, 1>(4, false, P, xc, xn, stream);
  run_layer<6, 4, 2>(5, false, P, xc, xn, stream);
  run_layer<4, 3, 1>(6, false, P, xc, xn, stream);
  run_layer<3, 1, 2>(7, true, P, xc, xn, stream);

  // head: S = relu(HL @ WS2^T + SB); Y1 = relu(S @ out1_w^T + out1_b); out = Y1 @ out2_w^T + out2_b
  dim3 g1((N + 127) / 128, 4);
  k_mgemm<<<g1, 256, 0, stream>>>(HL, BW1, SB, S, N, 256, 1);
  dim3 g2((N + 127) / 128, 8);
  k_mgemm<<<g2, 256, 0, stream>>>(S, BW2, out1_b, Y1, N, 512, 1);
  dim3 gf((N + 63) / 64, 8);
  k_final2<<<gf, 256, 0, stream>>>(Y1, out2_w, out2_b, (float*)d_out);
}

// Round 19
// 1019.035 us; speedup vs baseline: 1.1169x; 1.1169x over previous
//
#include <hip/hip_runtime.h>
#include <cmath>

// ---------------- problem constants ----------------
constexpr int N = 20000, T = 13, E = 320000;
constexpr int NB_SCAN = (N + 255) / 256;   // 79
constexpr int NPART = 64;                  // BN-sum partial buffers (atomic contention spread)
typedef unsigned int uint32;

typedef __attribute__((ext_vector_type(8))) short short8;   // 8 bf16 = 4 VGPRs
typedef __attribute__((ext_vector_type(4))) float f32x4;    // MFMA C/D frag

// ---------------- bf16 helpers ----------------
__device__ __forceinline__ unsigned short f2bf(float f) {
  unsigned int u = __float_as_uint(f);
  unsigned int r = (u + 0x7FFFu + ((u >> 16) & 1u)) >> 16;
  return (unsigned short)r;
}
__device__ __forceinline__ float bflo(uint32 v) { return __uint_as_float(v << 16); }
__device__ __forceinline__ float bfhi(uint32 v) { return __uint_as_float(v & 0xFFFF0000u); }
__device__ __forceinline__ uint32 packbf(float lo, float hi) {
  return (uint32)f2bf(lo) | ((uint32)f2bf(hi) << 16);
}

// ---------------- workspace layout ----------------
constexpr size_t WALIGN = 512;
constexpr size_t align_up(size_t x) { return (x + WALIGN - 1) & ~(WALIGN - 1); }

constexpr size_t XA_OFF  = 0;
constexpr size_t X_SZ    = align_up((size_t)N * 13 * 32 * 4);
constexpr size_t XB_OFF  = XA_OFF + X_SZ;
constexpr size_t H_OFF   = XB_OFF + X_SZ;
constexpr size_t H_SZ    = align_up((size_t)N * 12 * 32 * 4);
constexpr size_t C1_OFF  = H_OFF + H_SZ;
constexpr size_t C2_OFF  = C1_OFF + H_SZ;
constexpr size_t C3_OFF  = C2_OFF + H_SZ;
constexpr size_t HL_OFF  = C3_OFF + H_SZ;
constexpr size_t HL_SZ   = align_up((size_t)N * 256 * 4);
constexpr size_t WS2_OFF = HL_OFF + HL_SZ;
constexpr size_t SB_OFF  = WS2_OFF + align_up(256 * 256 * 4);
constexpr size_t SUMS_OFF = SB_OFF + align_up(256 * 4);          // 8 layers x NPART x 64 floats
constexpr size_t PAR_OFF  = SUMS_OFF + align_up(8 * NPART * 64 * 4);
constexpr size_t CNT_OFF  = PAR_OFF + align_up(9 * 64 * 4);
constexpr size_t ROW_OFF  = CNT_OFF + align_up((size_t)N * 4);
constexpr size_t FILL_OFF = ROW_OFF + align_up((size_t)(N + 1) * 4);
constexpr size_t COL_OFF  = FILL_OFF + align_up((size_t)N * 4);
constexpr size_t DEG_OFF  = COL_OFF + align_up((size_t)E * 4);
constexpr size_t BP_OFF   = DEG_OFF + align_up((size_t)N * 4);   // gc_w B-frag pack
constexpr size_t CP_OFF   = BP_OFF + align_up(8 * 2048 * 4);     // conv W-frag pack
constexpr size_t BW1_OFF  = CP_OFF + align_up(8 * 2176 * 4);     // WS2 B-frag pack (O=256)
constexpr size_t BW2_OFF  = BW1_OFF + align_up(32768 * 4);       // out1_w B-frag pack (O=512)
constexpr size_t BS_OFF   = BW2_OFF + align_up(65536 * 4);       // scan partials
constexpr size_t BO_OFF   = BS_OFF + align_up((size_t)NB_SCAN * 4); // scan offsets
// aliases used after all layers are done:
constexpr size_t S_OFF  = C2_OFF;   // N*256 floats
constexpr size_t Y1_OFF = H_OFF;    // N*512 floats (spans H+C1)

// ---------------- CSR build ----------------
__global__ void k_count(const int* __restrict__ dst, int* __restrict__ cnt) {
  int i = blockIdx.x * 256 + threadIdx.x;
  if (i < E) atomicAdd(&cnt[dst[i]], 1);
}

// parallel scan, phase 1: per-block sums
__global__ __launch_bounds__(256) void k_scan1(const int* __restrict__ cnt, int* __restrict__ bsum) {
  __shared__ int sc[256];
  int t = threadIdx.x; int idx = blockIdx.x * 256 + t;
  int v = (idx < N) ? cnt[idx] : 0;
  sc[t] = v; __syncthreads();
  for (int off = 1; off < 256; off <<= 1) {
    int u = (t >= off) ? sc[t - off] : 0;
    __syncthreads();
    sc[t] += u;
    __syncthreads();
  }
  if (t == 255) bsum[blockIdx.x] = sc[255];
}

// phase 2: exclusive scan of block sums (1 tiny block)
__global__ __launch_bounds__(256) void k_scan2(const int* __restrict__ bsum, int* __restrict__ boff) {
  __shared__ int sc[256];
  int t = threadIdx.x;
  int v = (t < NB_SCAN) ? bsum[t] : 0;
  sc[t] = v; __syncthreads();
  for (int off = 1; off < 256; off <<= 1) {
    int u = (t >= off) ? sc[t - off] : 0;
    __syncthreads();
    sc[t] += u;
    __syncthreads();
  }
  if (t < NB_SCAN) boff[t] = sc[t] - v;
  if (t == 255) boff[NB_SCAN] = sc[255];   // total
}

// phase 3: per-block exclusive scan + apply offsets
__global__ __launch_bounds__(256) void k_scan3(const int* __restrict__ cnt, const int* __restrict__ boff,
                                               int* __restrict__ rowptr, int* __restrict__ fill,
                                               float* __restrict__ deginv) {
  __shared__ int sc[256];
  int t = threadIdx.x; int idx = blockIdx.x * 256 + t;
  int v = (idx < N) ? cnt[idx] : 0;
  sc[t] = v; __syncthreads();
  for (int off = 1; off < 256; off <<= 1) {
    int u = (t >= off) ? sc[t - off] : 0;
    __syncthreads();
    sc[t] += u;
    __syncthreads();
  }
  if (idx < N) {
    int run = boff[blockIdx.x] + sc[t] - v;
    rowptr[idx] = run; fill[idx] = run;
    deginv[idx] = 1.0f / (float)(v > 1 ? v : 1);
  }
  if (blockIdx.x == 0 && t == 0) rowptr[N] = boff[NB_SCAN];
}

__global__ void k_scatter(const int* __restrict__ src, const int* __restrict__ dst,
                          int* __restrict__ fill, int* __restrict__ col) {
  int i = blockIdx.x * 256 + threadIdx.x;
  if (i < E) { int d = dst[i]; int p = atomicAdd(&fill[d], 1); col[p] = src[i]; }
}

__global__ void k_init_params(float* __restrict__ par) {
  int i = threadIdx.x;                 // 64 threads: slot 0 = identity affine
  par[i] = (i < 32) ? 1.0f : 0.0f;
}

// ---------------- pack gc_w into bf16 MFMA B-fragments (verified layout) ----------------
__global__ void k_prep_gcw(const float* __restrict__ gcw, uint32* __restrict__ bp) {
  int idx = blockIdx.x * 256 + threadIdx.x;
  if (idx >= 8 * 4 * 2 * 64 * 4) return;
  int w4 = idx & 3, lane = (idx >> 2) & 63, hh = (idx >> 8) & 1, s = (idx >> 9) & 3, l = idx >> 11;
  int n = lane & 15, q = lane >> 4;
  int k0 = q * 8 + w4 * 2, o = hh * 16 + n;
  const float* g = gcw + (((size_t)(l * 4 + s) * 32 + k0) * 32 + o);
  bp[idx] = packbf(g[0], g[32]);
}

// ---------------- pack a [O][256] fp32 weight into bf16 B-fragments ----------------
__global__ void k_prep_bw(const float* __restrict__ W, uint32* __restrict__ bp, int O) {
  int idx = blockIdx.x * 256 + threadIdx.x;
  int total = (O / 16) * 8 * 64 * 4;
  if (idx >= total) return;
  int w4 = idx & 3, lane = (idx >> 2) & 63, ks = (idx >> 8) & 7, ot = idx >> 11;
  int n = lane & 15, q = lane >> 4;
  int k = ks * 32 + q * 8 + w4 * 2;
  const float* wr = W + (size_t)(ot * 16 + n) * 256 + k;
  bp[idx] = packbf(wr[0], wr[1]);
}

// ---------------- pack conv weights (affine-folded) into bf16 B-fragments + biases ----------------
__global__ void k_prep_conv(const float* __restrict__ fw, const float* __restrict__ fb,
                            const float* __restrict__ gw, const float* __restrict__ gb,
                            const float* __restrict__ par, int layer, uint32* __restrict__ cpbuf) {
  uint32* base = cpbuf + (size_t)layer * 2176;
  int tid = blockIdx.x * 256 + threadIdx.x;
  if (tid < 2048) {
    int w4 = tid & 3, lane = (tid >> 2) & 63, hh = (tid >> 8) & 1, ktap = (tid >> 9) & 1, sel = tid >> 10;
    int n = lane & 15, q = lane >> 4;
    int c0 = q * 8 + w4 * 2, o = hh * 16 + n;
    const float* w = sel ? gw : fw;
    float sc0 = par[layer * 64 + c0], sc1 = par[layer * 64 + c0 + 1];
    float v0 = w[(((size_t)layer * 32 + o) * 32 + c0) * 2 + ktap] * sc0;
    float v1 = w[(((size_t)layer * 32 + o) * 32 + c0 + 1) * 2 + ktap] * sc1;
    base[tid] = packbf(v0, v1);
  } else if (tid < 2048 + 64) {
    int i = tid - 2048; int sel = i >> 5; int o = i & 31;
    const float* w = sel ? gw : fw;
    const float* b = sel ? gb : fb;
    float s = b[layer * 32 + o];
    for (int c = 0; c < 32; c++) {
      float sh = par[layer * 64 + 32 + c];
      s += (w[(((size_t)layer * 32 + o) * 32 + c) * 2 + 0] +
            w[(((size_t)layer * 32 + o) * 32 + c) * 2 + 1]) * sh;
    }
    ((float*)base)[2048 + i] = s;
  }
}

// ---------------- enter 1x1 conv: inputs [N,T,3] -> x bf16 [n][t][c] ----------------
__global__ void k_enter(const float* __restrict__ in, const float* __restrict__ w,
                        const float* __restrict__ b, uint32* __restrict__ x) {
  int idx = blockIdx.x * 256 + threadIdx.x;
  if (idx >= N * 13 * 16) return;
  int cw = idx & 15; int tmp = idx >> 4; int t = tmp % 13; int n = tmp / 13;
  int c0 = cw * 2;
  const float* ip = in + (size_t)n * (13 * 3) + t * 3;
  float v0 = b[c0]     + w[c0 * 3 + 0]       * ip[0] + w[c0 * 3 + 1]       * ip[1] + w[c0 * 3 + 2]       * ip[2];
  float v1 = b[c0 + 1] + w[(c0 + 1) * 3 + 0] * ip[0] + w[(c0 + 1) * 3 + 1] * ip[1] + w[(c0 + 1) * 3 + 2] * ip[2];
  x[idx] = packbf(v0, v1);
}

// ---------------- gated dilated conv (MFMA) — round-15 proven form ----------------
template <int TIN, int TOUT, int D>
__global__ __launch_bounds__(256, 4) void k_conv(const uint32* __restrict__ x,
    const uint32* __restrict__ cpbuf, int layer,
    uint32* __restrict__ h, float* __restrict__ hlast) {
  constexpr int RS = 34;
  __shared__ float xst[128 * RS];
  int tid = threadIdx.x;
  int wave = tid >> 6, lane = tid & 63;
  int m = lane & 15, q = lane >> 4;
  int nrows = N * TOUT;
  int base = blockIdx.x * 128;

  const uint32* cp = cpbuf + (size_t)layer * 2176;
  short8 bf[2][2][2];   // [sel][ktap][hh]
#pragma unroll
  for (int sel = 0; sel < 2; sel++)
#pragma unroll
    for (int kt = 0; kt < 2; kt++)
#pragma unroll
      for (int hh = 0; hh < 2; hh++)
        bf[sel][kt][hh] = *(const short8*)(cp + (size_t)(((sel * 2 + kt) * 2 + hh) * 64 + lane) * 4);
  const float* bias = (const float*)(cp + 2048);
  float fb0 = bias[m], fb1 = bias[16 + m], gb0 = bias[32 + m], gb1 = bias[48 + m];

#pragma unroll
  for (int tile = 0; tile < 2; tile++) {
    int row = base + wave * 32 + tile * 16 + m;
    bool valid = row < nrows;
    int rr = valid ? row : 0;
    int n = rr / TOUT, tt = rr - n * TOUT;
    const uint32* xr = x + ((size_t)n * TIN + tt) * 16 + q * 4;
    short8 a0 = {0,0,0,0,0,0,0,0}, aD = {0,0,0,0,0,0,0,0};
    if (valid) { a0 = *(const short8*)xr; aD = *(const short8*)(xr + D * 16); }
    f32x4 aF0 = {0.f,0.f,0.f,0.f}, aF1 = {0.f,0.f,0.f,0.f};
    f32x4 aG0 = {0.f,0.f,0.f,0.f}, aG1 = {0.f,0.f,0.f,0.f};
    aF0 = __builtin_amdgcn_mfma_f32_16x16x32_bf16(a0, bf[0][0][0], aF0, 0, 0, 0);
    aF0 = __builtin_amdgcn_mfma_f32_16x16x32_bf16(aD, bf[0][1][0], aF0, 0, 0, 0);
    aF1 = __builtin_amdgcn_mfma_f32_16x16x32_bf16(a0, bf[0][0][1], aF1, 0, 0, 0);
    aF1 = __builtin_amdgcn_mfma_f32_16x16x32_bf16(aD, bf[0][1][1], aF1, 0, 0, 0);
    aG0 = __builtin_amdgcn_mfma_f32_16x16x32_bf16(a0, bf[1][0][0], aG0, 0, 0, 0);
    aG0 = __builtin_amdgcn_mfma_f32_16x16x32_bf16(aD, bf[1][1][0], aG0, 0, 0, 0);
    aG1 = __builtin_amdgcn_mfma_f32_16x16x32_bf16(a0, bf[1][0][1], aG1, 0, 0, 0);
    aG1 = __builtin_amdgcn_mfma_f32_16x16x32_bf16(aD, bf[1][1][1], aG1, 0, 0, 0);
#pragma unroll
    for (int r = 0; r < 4; r++) {
      int lrow = wave * 32 + tile * 16 + q * 4 + r;
      float F0 = aF0[r] + fb0, G0 = aG0[r] + gb0;
      float F1 = aF1[r] + fb1, G1 = aG1[r] + gb1;
      float af0 = fabsf(F0), ef0 = __expf(-2.0f * af0);
      float th0 = copysignf((1.0f - ef0) / (1.0f + ef0), F0);
      float hv0 = th0 * (1.0f / (1.0f + __expf(-G0)));
      float af1 = fabsf(F1), ef1 = __expf(-2.0f * af1);
      float th1 = copysignf((1.0f - ef1) / (1.0f + ef1), F1);
      float hv1 = th1 * (1.0f / (1.0f + __expf(-G1)));
      xst[lrow * RS + m]      = hv0;
      xst[lrow * RS + 16 + m] = hv1;
    }
  }
  __syncthreads();
  {
    uint2* outp = (uint2*)h;
#pragma unroll
    for (int it = 0; it < 4; it++) {
      int l = it * 256 + tid;
      int g = base * 8 + l;
      if (g < nrows * 8) {
        int rl = l >> 3, j4 = l & 7;
        float2 a = *(const float2*)&xst[rl * RS + j4 * 4];
        float2 b = *(const float2*)&xst[rl * RS + j4 * 4 + 2];
        outp[g] = make_uint2(packbf(a.x, a.y), packbf(b.x, b.y));
        int grow = base + rl;
        int node = grow / TOUT, tt = grow - node * TOUT;
        if (tt == TOUT - 1) {
          *(float4*)(hlast + (size_t)node * 256 + layer * 32 + j4 * 4) = make_float4(a.x, a.y, b.x, b.y);
        }
      }
    }
  }
}

// ---------------- one diffusion hop (bf16, fp32 accumulate, x8 edge unroll) ----------------
template <int F>
__global__ __launch_bounds__(256) void k_hop(const uint32* __restrict__ in, uint32* __restrict__ out,
    const int* __restrict__ rowptr, const int* __restrict__ col, const float* __restrict__ deginv) {
  constexpr int F2 = F / 2;
  constexpr int NW = (F2 + 63) / 64;
  int wid = (blockIdx.x * 256 + threadIdx.x) >> 6;
  int lane = threadIdx.x & 63;
  if (wid >= N) return;
  int s = rowptr[wid], e = rowptr[wid + 1];
  float alo[NW], ahi[NW];
#pragma unroll
  for (int k = 0; k < NW; k++) { alo[k] = 0.0f; ahi[k] = 0.0f; }
  int idx = s;
  for (; idx + 7 < e; idx += 8) {
    const uint32* p[8];
#pragma unroll
    for (int q = 0; q < 8; q++) p[q] = in + (size_t)col[idx + q] * F2;
    uint32 v[8][NW];
#pragma unroll
    for (int q = 0; q < 8; q++) {
#pragma unroll
      for (int k = 0; k < NW; k++) {
        int j = k * 64 + lane;
        v[q][k] = (j < F2) ? p[q][j] : 0u;
      }
    }
#pragma unroll
    for (int k = 0; k < NW; k++) {
      alo[k] += ((bflo(v[0][k]) + bflo(v[1][k])) + (bflo(v[2][k]) + bflo(v[3][k]))) +
                ((bflo(v[4][k]) + bflo(v[5][k])) + (bflo(v[6][k]) + bflo(v[7][k])));
      ahi[k] += ((bfhi(v[0][k]) + bfhi(v[1][k])) + (bfhi(v[2][k]) + bfhi(v[3][k]))) +
                ((bfhi(v[4][k]) + bfhi(v[5][k])) + (bfhi(v[6][k]) + bfhi(v[7][k])));
    }
  }
  for (; idx + 3 < e; idx += 4) {
    const uint32* p0 = in + (size_t)col[idx] * F2;
    const uint32* p1 = in + (size_t)col[idx + 1] * F2;
    const uint32* p2 = in + (size_t)col[idx + 2] * F2;
    const uint32* p3 = in + (size_t)col[idx + 3] * F2;
#pragma unroll
    for (int k = 0; k < NW; k++) {
      int j = k * 64 + lane;
      if (j < F2) {
        uint32 v0 = p0[j], v1 = p1[j], v2 = p2[j], v3 = p3[j];
        alo[k] += (bflo(v0) + bflo(v1)) + (bflo(v2) + bflo(v3));
        ahi[k] += (bfhi(v0) + bfhi(v1)) + (bfhi(v2) + bfhi(v3));
      }
    }
  }
  for (; idx < e; ++idx) {
    const uint32* p = in + (size_t)col[idx] * F2;
#pragma unroll
    for (int k = 0; k < NW; k++) {
      int j = k * 64 + lane;
      if (j < F2) { uint32 v = p[j]; alo[k] += bflo(v); ahi[k] += bfhi(v); }
    }
  }
  float inv = deginv[wid];
  uint32* q = out + (size_t)wid * F2;
#pragma unroll
  for (int k = 0; k < NW; k++) {
    int j = k * 64 + lane;
    if (j < F2) q[j] = packbf(alo[k] * inv, ahi[k] * inv);
  }
}

// ---------------- combine (MFMA) — partial-buffer BN atomics (contention 1875 -> ~30) ----------------
template <int TIN, int TOUT>
__global__ __launch_bounds__(256, 4) void k_combine(const uint32* __restrict__ h,
    const uint32* __restrict__ c1, const uint32* __restrict__ c2, const uint32* __restrict__ c3,
    const uint32* __restrict__ bpack, const float* __restrict__ gcb,
    const uint32* __restrict__ xcur, int layer,
    const float* __restrict__ par, int slot,
    uint32* __restrict__ xnext, float* __restrict__ sums) {
  constexpr int RS = 34;
  __shared__ float xst[128 * RS];
  __shared__ float pbuf[96];
  __shared__ float r1s[32], r2s[32];
  int tid = threadIdx.x;
  if (tid < 32) {
    pbuf[tid]      = gcb[layer * 32 + tid];
    pbuf[32 + tid] = par[slot * 64 + tid];
    pbuf[64 + tid] = par[slot * 64 + 32 + tid];
    r1s[tid] = 0.0f; r2s[tid] = 0.0f;
  }

  int nrows = N * TOUT;
  int base = blockIdx.x * 128;
  int wave = tid >> 6, lane = tid & 63;
  int m = lane & 15, q = lane >> 4;

  const uint32* bp = bpack + (size_t)layer * 2048;
  short8 bf[4][2];
#pragma unroll
  for (int s = 0; s < 4; s++)
#pragma unroll
    for (int hh = 0; hh < 2; hh++)
      bf[s][hh] = *(const short8*)(bp + (size_t)((s * 2 + hh) * 64 + lane) * 4);

  f32x4 acc[2][2] = {{{0.f,0.f,0.f,0.f},{0.f,0.f,0.f,0.f}},{{0.f,0.f,0.f,0.f},{0.f,0.f,0.f,0.f}}};
  const uint32* srcs[4] = { h, c1, c2, c3 };
#pragma unroll
  for (int s = 0; s < 4; s++) {
    const uint32* sp = srcs[s];
#pragma unroll
    for (int t = 0; t < 2; t++) {
      int row = base + wave * 32 + t * 16 + m;
      short8 af = {0,0,0,0,0,0,0,0};
      if (row < nrows) af = *(const short8*)(sp + (size_t)row * 16 + q * 4);
      acc[t][0] = __builtin_amdgcn_mfma_f32_16x16x32_bf16(af, bf[s][0], acc[t][0], 0, 0, 0);
      acc[t][1] = __builtin_amdgcn_mfma_f32_16x16x32_bf16(af, bf[s][1], acc[t][1], 0, 0, 0);
    }
  }

  __syncthreads();
#pragma unroll
  for (int t = 0; t < 2; t++)
#pragma unroll
    for (int hh = 0; hh < 2; hh++)
#pragma unroll
      for (int r = 0; r < 4; r++)
        xst[(wave * 32 + t * 16 + q * 4 + r) * RS + hh * 16 + m] = acc[t][hh][r];
  __syncthreads();

  constexpr int toff = TIN - TOUT;
  int rg = tid >> 3, oq = tid & 7;
  float gb0 = pbuf[oq * 4 + 0], gb1 = pbuf[oq * 4 + 1], gb2 = pbuf[oq * 4 + 2], gb3 = pbuf[oq * 4 + 3];
  float sc0 = pbuf[32 + oq * 4 + 0], sc1 = pbuf[32 + oq * 4 + 1], sc2 = pbuf[32 + oq * 4 + 2], sc3 = pbuf[32 + oq * 4 + 3];
  float sh0 = pbuf[64 + oq * 4 + 0], sh1 = pbuf[64 + oq * 4 + 1], sh2 = pbuf[64 + oq * 4 + 2], sh3 = pbuf[64 + oq * 4 + 3];
  float s1[4] = {0.f, 0.f, 0.f, 0.f}, s2[4] = {0.f, 0.f, 0.f, 0.f};
#pragma unroll
  for (int i = 0; i < 4; i++) {
    int r = rg + 32 * i;
    int row = base + r;
    bool act = row < nrows;
    float2 aa = *(const float2*)&xst[r * RS + oq * 4];
    float2 ab = *(const float2*)&xst[r * RS + oq * 4 + 2];
    float xr0 = 0.f, xr1 = 0.f, xr2 = 0.f, xr3 = 0.f;
    if (act) {
      int node = row / TOUT, t_ = row - node * TOUT;
      const uint32* rp = xcur + ((size_t)node * TIN + toff + t_) * 16 + oq * 2;
      uint32 va = rp[0], vb = rp[1];
      xr0 = bflo(va); xr1 = bfhi(va); xr2 = bflo(vb); xr3 = bfhi(vb);
    }
    float v0 = aa.x + gb0 + sc0 * xr0 + sh0;
    float v1 = aa.y + gb1 + sc1 * xr1 + sh1;
    float v2 = ab.x + gb2 + sc2 * xr2 + sh2;
    float v3 = ab.y + gb3 + sc3 * xr3 + sh3;
    *(float2*)&xst[r * RS + oq * 4]     = make_float2(v0, v1);
    *(float2*)&xst[r * RS + oq * 4 + 2] = make_float2(v2, v3);
    if (act) {
      s1[0] += v0; s1[1] += v1; s1[2] += v2; s1[3] += v3;
      s2[0] += v0 * v0; s2[1] += v1 * v1; s2[2] += v2 * v2; s2[3] += v3 * v3;
    }
  }
#pragma unroll
  for (int j = 0; j < 4; j++) {
    atomicAdd(&r1s[oq * 4 + j], s1[j]);
    atomicAdd(&r2s[oq * 4 + j], s2[j]);
  }
  __syncthreads();

  {
    uint2* outp = (uint2*)xnext;
#pragma unroll
    for (int it = 0; it < 4; it++) {
      int l = it * 256 + tid;
      int g = base * 8 + l;
      if (g < nrows * 8) {
        int rl = l >> 3, j4 = l & 7;
        float2 a = *(const float2*)&xst[rl * RS + j4 * 4];
        float2 b = *(const float2*)&xst[rl * RS + j4 * 4 + 2];
        outp[g] = make_uint2(packbf(a.x, a.y), packbf(b.x, b.y));
      }
    }
  }
  // BN partial atomics spread over NPART buffers: sums[(layer*NPART+part)*64 + j]
  {
    int part = blockIdx.x & (NPART - 1);
    float* sp = sums + ((size_t)layer * NPART + part) * 64;
    if (tid < 32) atomicAdd(&sp[tid], r1s[tid]);
    else if (tid < 64) atomicAdd(&sp[tid], r2s[tid - 32]);
  }
}

// ---------------- BN stats (reduce NPART partials) -> affine params for next slot ----------------
__global__ void k_bnfin(const float* __restrict__ sums, const float* __restrict__ bng,
                        const float* __restrict__ bnb, float* __restrict__ par,
                        int layer, int tout) {
  int o = threadIdx.x;  // 32
  float cnt = (float)N * (float)tout;
  float s1 = 0.0f, s2 = 0.0f;
  const float* lp = sums + (size_t)layer * NPART * 64;
  for (int p = 0; p < NPART; p++) {
    s1 += lp[p * 64 + o];
    s2 += lp[p * 64 + 32 + o];
  }
  float mu = s1 / cnt;
  float var = s2 / cnt - mu * mu;
  float sc = bng[layer * 32 + o] * rsqrtf(var + 1e-5f);
  par[(layer + 1) * 64 + o] = sc;
  par[(layer + 1) * 64 + 32 + o] = bnb[layer * 32 + o] - mu * sc;
}

// ---------------- head prep ----------------
__global__ void k_prep_skipw(const float* __restrict__ sw, float* __restrict__ w2) {
  int idx = blockIdx.x * 256 + threadIdx.x;
  if (idx >= 8 * 256 * 32) return;
  int l = idx / (256 * 32), r = idx % (256 * 32), o = r / 32, c = r & 31;
  w2[o * 256 + l * 32 + c] = sw[idx];
}
__global__ void k_prep_sb(const float* __restrict__ sb, float* __restrict__ out) {
  int o = threadIdx.x;  // 256
  float s = 0.0f;
  for (int l = 0; l < 8; l++) s += sb[l * 256 + o];
  out[o] = s;
}

// ---------------- head GEMM (MFMA) ----------------
__global__ __launch_bounds__(256) void k_mgemm(const float* __restrict__ A, const uint32* __restrict__ bp,
    const float* __restrict__ bias, float* __restrict__ C, int M, int Onum, int relu) {
  constexpr int RS = 68;
  __shared__ float xst[128 * RS];
  int tid = threadIdx.x;
  int wave = tid >> 6, lane = tid & 63;
  int m = lane & 15, q = lane >> 4;
  int base = blockIdx.x * 128;
  int ot0 = blockIdx.y * 4;

  f32x4 acc[2][4];
#pragma unroll
  for (int t = 0; t < 2; t++)
#pragma unroll
    for (int nt = 0; nt < 4; nt++) acc[t][nt] = (f32x4){0.f, 0.f, 0.f, 0.f};

#pragma unroll 1
  for (int ks = 0; ks < 8; ks++) {
    short8 a[2];
#pragma unroll
    for (int t = 0; t < 2; t++) {
      int row = base + wave * 32 + t * 16 + m;
      float4 f0 = make_float4(0.f, 0.f, 0.f, 0.f), f1 = f0;
      if (row < M) {
        const float* ap = A + (size_t)row * 256 + ks * 32 + q * 8;
        f0 = *(const float4*)ap;
        f1 = *(const float4*)(ap + 4);
      }
      uint32 u[4];
      u[0] = packbf(f0.x, f0.y); u[1] = packbf(f0.z, f0.w);
      u[2] = packbf(f1.x, f1.y); u[3] = packbf(f1.z, f1.w);
      a[t] = *(const short8*)u;
    }
#pragma unroll
    for (int nt = 0; nt < 4; nt++) {
      short8 b = *(const short8*)(bp + (size_t)(((ot0 + nt) * 8 + ks) * 64 + lane) * 4);
      acc[0][nt] = __builtin_amdgcn_mfma_f32_16x16x32_bf16(a[0], b, acc[0][nt], 0, 0, 0);
      acc[1][nt] = __builtin_amdgcn_mfma_f32_16x16x32_bf16(a[1], b, acc[1][nt], 0, 0, 0);
    }
  }

#pragma unroll
  for (int t = 0; t < 2; t++)
#pragma unroll
    for (int nt = 0; nt < 4; nt++) {
      float bv = bias[blockIdx.y * 64 + nt * 16 + m];
#pragma unroll
      for (int r = 0; r < 4; r++) {
        float v = acc[t][nt][r] + bv;
        if (relu) v = fmaxf(v, 0.0f);
        xst[(wave * 32 + t * 16 + q * 4 + r) * RS + nt * 16 + m] = v;
      }
    }
  __syncthreads();

#pragma unroll
  for (int it = 0; it < 8; it++) {
    int l = it * 256 + tid;
    int rl = l >> 4, c4 = l & 15;
    int grow = base + rl;
    if (grow < M) {
      float4 v = *(const float4*)&xst[rl * RS + c4 * 4];
      *(float4*)(C + (size_t)grow * Onum + blockIdx.y * 64 + c4 * 4) = v;
    }
  }
}

// ---------------- final: K-split tiled GEMM with atomic reduce -> d_out [N,24] ----------------
__global__ __launch_bounds__(256) void k_final2(const float* __restrict__ Y1, const float* __restrict__ W2,
                                                const float* __restrict__ b2, float* __restrict__ out) {
  __shared__ float y1s[64][68];
  __shared__ float w2s[24][65];
  int tid = threadIdx.x;
  int bm = blockIdx.x * 64;
  int k0 = blockIdx.y * 64;
  for (int i = tid; i < 64 * 16; i += 256) {
    int r = i >> 4, k4 = i & 15;
    int gm = bm + r;
    float4 v = make_float4(0.f, 0.f, 0.f, 0.f);
    if (gm < N) v = *(const float4*)(Y1 + (size_t)gm * 512 + k0 + k4 * 4);
    y1s[r][k4 * 4 + 0] = v.x; y1s[r][k4 * 4 + 1] = v.y;
    y1s[r][k4 * 4 + 2] = v.z; y1s[r][k4 * 4 + 3] = v.w;
  }
  for (int i = tid; i < 24 * 16; i += 256) {
    int o = i >> 4, k4 = i & 15;
    float4 v = *(const float4*)(W2 + (size_t)o * 512 + k0 + k4 * 4);
    w2s[o][k4 * 4 + 0] = v.x; w2s[o][k4 * 4 + 1] = v.y;
    w2s[o][k4 * 4 + 2] = v.z; w2s[o][k4 * 4 + 3] = v.w;
  }
  __syncthreads();
  int rg = tid >> 5;
  int o = tid & 31;
  if (o < 24) {
    float acc[8] = {};
    for (int kk = 0; kk < 64; kk++) {
      float w = w2s[o][kk];
#pragma unroll
      for (int i = 0; i < 8; i++) acc[i] += y1s[rg * 8 + i][kk] * w;
    }
    float bias = (blockIdx.y == 0) ? b2[o] : 0.0f;
#pragma unroll
    for (int i = 0; i < 8; i++) {
      int gm = bm + rg * 8 + i;
      if (gm < N) atomicAdd(&out[(size_t)gm * 24 + o], acc[i] + bias);
    }
  }
}

// ---------------- host side ----------------
struct Ptrs {
  const float *fw, *fb, *gw, *gb, *gcb, *bng, *bnb;
  const uint32 *bpack;
  uint32 *cpack;
  void *H, *C1, *C2, *C3;
  float *HL, *par, *sums;
  const int *row, *col;
  const float *deg;
};

template <int TIN, int TOUT, int D>
static void run_layer(int layer, bool last, const Ptrs& P, uint32*& xc, uint32*& xn, hipStream_t stream) {
  int cblocks = (N * TOUT + 127) / 128;
  k_conv<TIN, TOUT, D><<<cblocks, 256, 0, stream>>>(xc, P.cpack, layer, (uint32*)P.H, P.HL);
  if (!last) {
    constexpr int F = TOUT * 32;
    int hb = (N * 64 + 255) / 256;
    k_hop<F><<<hb, 256, 0, stream>>>((const uint32*)P.H, (uint32*)P.C1, P.row, P.col, P.deg);
    k_hop<F><<<hb, 256, 0, stream>>>((const uint32*)P.C1, (uint32*)P.C2, P.row, P.col, P.deg);
    k_hop<F><<<hb, 256, 0, stream>>>((const uint32*)P.C2, (uint32*)P.C3, P.row, P.col, P.deg);
    k_combine<TIN, TOUT><<<cblocks, 256, 0, stream>>>((const uint32*)P.H, (const uint32*)P.C1,
                                                      (const uint32*)P.C2, (const uint32*)P.C3,
                                                      P.bpack, P.gcb, xc, layer, P.par, layer, xn, P.sums);
    k_bnfin<<<1, 32, 0, stream>>>(P.sums, P.bng, P.bnb, P.par, layer, TOUT);
    k_prep_conv<<<9, 256, 0, stream>>>(P.fw, P.fb, P.gw, P.gb, P.par, layer + 1, P.cpack);
    uint32* tmp = xc; xc = xn; xn = tmp;
  }
}

extern "C" void kernel_launch(void* const* d_in, const int* in_sizes, int n_in,
                              void* d_out, int out_size, void* d_ws, size_t ws_size,
                              hipStream_t stream) {
  const float* inputs  = (const float*)d_in[0];
  const int*   esrc    = (const int*)d_in[1];
  const int*   edst    = (const int*)d_in[2];
  const float* enter_w = (const float*)d_in[3];
  const float* enter_b = (const float*)d_in[4];
  const float* filt_w  = (const float*)d_in[5];
  const float* filt_b  = (const float*)d_in[6];
  const float* gate_w  = (const float*)d_in[7];
  const float* gate_b  = (const float*)d_in[8];
  const float* gc_w    = (const float*)d_in[9];
  const float* gc_b    = (const float*)d_in[10];
  const float* skip_w  = (const float*)d_in[11];
  const float* skip_b  = (const float*)d_in[12];
  const float* bn_g    = (const float*)d_in[13];
  const float* bn_b    = (const float*)d_in[14];
  const float* out1_w  = (const float*)d_in[15];
  const float* out1_b  = (const float*)d_in[16];
  const float* out2_w  = (const float*)d_in[17];
  const float* out2_b  = (const float*)d_in[18];

  char* ws = (char*)d_ws;
  uint32* XA = (uint32*)(ws + XA_OFF);
  uint32* XB = (uint32*)(ws + XB_OFF);
  void* H    = (void*)(ws + H_OFF);
  void* C1   = (void*)(ws + C1_OFF);
  void* C2   = (void*)(ws + C2_OFF);
  void* C3   = (void*)(ws + C3_OFF);
  float* HL  = (float*)(ws + HL_OFF);
  float* WS2 = (float*)(ws + WS2_OFF);
  float* SB  = (float*)(ws + SB_OFF);
  float* SUMS = (float*)(ws + SUMS_OFF);
  float* PAR  = (float*)(ws + PAR_OFF);
  int* CNT  = (int*)(ws + CNT_OFF);
  int* ROW  = (int*)(ws + ROW_OFF);
  int* FILL = (int*)(ws + FILL_OFF);
  int* COL  = (int*)(ws + COL_OFF);
  float* DEG = (float*)(ws + DEG_OFF);
  uint32* BP = (uint32*)(ws + BP_OFF);
  uint32* CP = (uint32*)(ws + CP_OFF);
  uint32* BW1 = (uint32*)(ws + BW1_OFF);
  uint32* BW2 = (uint32*)(ws + BW2_OFF);
  int* BS = (int*)(ws + BS_OFF);
  int* BO = (int*)(ws + BO_OFF);
  float* S  = (float*)(ws + S_OFF);
  float* Y1 = (float*)(ws + Y1_OFF);

  hipMemsetAsync(CNT, 0, (size_t)N * 4, stream);
  hipMemsetAsync(SUMS, 0, (size_t)8 * NPART * 64 * 4, stream);
  hipMemsetAsync(d_out, 0, (size_t)out_size * 4, stream);

  k_count<<<(E + 255) / 256, 256, 0, stream>>>(edst, CNT);
  k_scan1<<<NB_SCAN, 256, 0, stream>>>(CNT, BS);
  k_scan2<<<1, 256, 0, stream>>>(BS, BO);
  k_scan3<<<NB_SCAN, 256, 0, stream>>>(CNT, BO, ROW, FILL, DEG);
  k_scatter<<<(E + 255) / 256, 256, 0, stream>>>(esrc, edst, FILL, COL);
  k_init_params<<<1, 64, 0, stream>>>(PAR);
  k_prep_gcw<<<(8 * 4 * 2 * 64 * 4 + 255) / 256, 256, 0, stream>>>(gc_w, BP);
  k_prep_conv<<<9, 256, 0, stream>>>(filt_w, filt_b, gate_w, gate_b, PAR, 0, CP);
  k_enter<<<(N * 13 * 16 + 255) / 256, 256, 0, stream>>>(inputs, enter_w, enter_b, XA);
  k_prep_skipw<<<(8 * 256 * 32 + 255) / 256, 256, 0, stream>>>(skip_w, WS2);
  k_prep_sb<<<1, 256, 0, stream>>>(skip_b, SB);
  k_prep_bw<<<(32768 + 255) / 256, 256, 0, stream>>>(WS2, BW1, 256);
  k_prep_bw<<<(65536 + 255) / 256, 256, 0, stream>>>(out1_w, BW2, 512);

  Ptrs P;
  P.fw = filt_w; P.fb = filt_b; P.gw = gate_w; P.gb = gate_b;
  P.gcb = gc_b; P.bng = bn_g; P.bnb = bn_b; P.bpack = BP; P.cpack = CP;
  P.H = H; P.C1 = C1; P.C2 = C2; P.C3 = C3; P.HL = HL; P.par = PAR; P.sums = SUMS;
  P.row = ROW; P.col = COL; P.deg = DEG;

  uint32* xc = XA; uint32* xn = XB;
  run_layer<13, 12, 1>(0, false, P, xc, xn, stream);
  run_layer<12, 10, 2>(1, false, P, xc, xn, stream);
  run_layer<10, 9, 1>(2, false, P, xc, xn, stream);
  run_layer<9, 7, 2>(3, false, P, xc, xn, stream);
  run_layer<7, 6, 1>(4, false, P, xc, xn, stream);
  run_layer<6, 4, 2>(5, false, P, xc, xn, stream);
  run_layer<4, 3, 1>(6, false, P, xc, xn, stream);
  run_layer<3, 1, 2>(7, true, P, xc, xn, stream);

  // head: S = relu(HL @ WS2^T + SB); Y1 = relu(S @ out1_w^T + out1_b); out = Y1 @ out2_w^T + out2_b
  dim3 g1((N + 127) / 128, 4);
  k_mgemm<<<g1, 256, 0, stream>>>(HL, BW1, SB, S, N, 256, 1);
  dim3 g2((N + 127) / 128, 8);
  k_mgemm<<<g2, 256, 0, stream>>>(S, BW2, out1_b, Y1, N, 512, 1);
  dim3 gf((N + 63) / 64, 8);
  k_final2<<<gf, 256, 0, stream>>>(Y1, out2_w, out2_b, (float*)d_out);
}